// Round 7
// baseline (70.069 us; speedup 1.0000x reference)
//
#include <hip/hip_runtime.h>
#include <hip/hip_bf16.h>
#include <stdint.h>

#define NROWS 100000
#define INDIM 512
#define HID 128
#define NCLS 10
#define LEAKY_ALPHA 0.2f

typedef __bf16 bf16x8_t __attribute__((ext_vector_type(8)));
typedef __bf16 bf16x4_t __attribute__((ext_vector_type(4)));
typedef float f32x4_t __attribute__((ext_vector_type(4)));
typedef unsigned short ushort8_t __attribute__((ext_vector_type(8)));

union Frag {
    bf16x8_t v8;
    bf16x4_t v4[2];
    unsigned short u[8];
};

__device__ __forceinline__ unsigned short f2bf(float x) {
    union { __hip_bfloat16 b; unsigned short u; } cv;
    cv.b = __float2bfloat16(x);
    return cv.u;
}

// Byte address inside an [R x 32] bf16 tile image (rows paired into 128-B
// lines, 16-B units XOR-swizzled by pair&7). Bank-verified round 3.
__device__ __forceinline__ int img_addr(int r, int kk) {
    int p = r >> 1;
    int o = ((r & 1) << 6) | (kk << 1);
    return (p << 7) | ((((o >> 4) ^ (p & 7)) << 4) | (o & 15));
}

__device__ __forceinline__ void gload_lds16(const void* g, void* l) {
    __builtin_amdgcn_global_load_lds(
        (const __attribute__((address_space(1))) unsigned int*)g,
        (__attribute__((address_space(3))) unsigned int*)l, 16, 0, 0);
}

// ---------------- prep: Qimg = swizzled tile images of Q = [C@(W1@V) | C@(W2@V)] ----------------
__global__ __launch_bounds__(256) void k_prep(
    const float* __restrict__ C, const float* __restrict__ W, const float* __restrict__ V,
    unsigned short* __restrict__ Qimg) {
    __shared__ float Vl[HID * NCLS];
    __shared__ float Pl[2][HID][10];
    __shared__ float Cl[64][132];

    const int tid = threadIdx.x, b = blockIdx.x;
    for (int i = tid; i < HID * NCLS; i += 256) Vl[i] = V[i];
    __syncthreads();

    {
        const int half = tid >> 7, j = tid & 127;
        const float* wr = W + (half * HID + j) * HID;
        float s[NCLS];
#pragma unroll
        for (int c = 0; c < NCLS; ++c) s[c] = 0.f;
        for (int m = 0; m < HID; m += 4) {
            float4 wv = *reinterpret_cast<const float4*>(wr + m);
            float wa[4] = {wv.x, wv.y, wv.z, wv.w};
#pragma unroll
            for (int u = 0; u < 4; ++u)
#pragma unroll
                for (int c = 0; c < NCLS; ++c) s[c] += wa[u] * Vl[(m + u) * NCLS + c];
        }
#pragma unroll
        for (int c = 0; c < NCLS; ++c) Pl[half][j][c] = s[c];
    }
    const int k0 = b << 6;
    {
        const int kr = tid >> 2, seg = (tid & 3) << 5;
        const float4* src = reinterpret_cast<const float4*>(C + (k0 + kr) * HID + seg);
#pragma unroll
        for (int j = 0; j < 8; ++j)
            *reinterpret_cast<float4*>(&Cl[kr][seg + 4 * j]) = src[j];
    }
    __syncthreads();

    for (int e = tid; e < 64 * 32; e += 256) {
        const int n = e >> 6, kl = e & 63;
        const int half = n >> 4, c = n & 15;
        float s = 0.f;
        if (c < NCLS) {
#pragma unroll 4
            for (int j = 0; j < HID; ++j) s += Cl[kl][j] * Pl[half][j][c];
        }
        const int k = k0 + kl, t = k >> 5, kk = k & 31;
        *(unsigned short*)((char*)Qimg + t * 2048 + img_addr(n, kk)) = f2bf(s);
    }
}

// ---------------- thin GEMM: g = f @ Q, A direct global->reg->MFMA ----------------
// 4 waves x 32 rows = 128 rows/block. A-fragments loaded straight from global
// (coalesced by construction of the MFMA A-layout), converted in-register;
// depth-3 named register queue; NO barriers in the main loop. Q in LDS (32 KB).
#define LOADC(dst, t)                                                        \
    dst[0] = *reinterpret_cast<const float4*>(a0 + (t) * 32);                \
    dst[1] = *reinterpret_cast<const float4*>(a0 + (t) * 32 + 16);           \
    dst[2] = *reinterpret_cast<const float4*>(a1 + (t) * 32);                \
    dst[3] = *reinterpret_cast<const float4*>(a1 + (t) * 32 + 16);

#define CVT(fa, s)                                                           \
    {                                                                        \
        _Pragma("unroll")                                                    \
        for (int e = 0; e < 4; ++e) {                                        \
            fa[0].u[e]     = f2bf(s[0][e]);                                  \
            fa[0].u[4 + e] = f2bf(s[1][e]);                                  \
            fa[1].u[e]     = f2bf(s[2][e]);                                  \
            fa[1].u[4 + e] = f2bf(s[3][e]);                                  \
        }                                                                    \
    }

__global__ __launch_bounds__(256, 3) void k_gemm(
    const float* __restrict__ A,             // [NROWS][512] f32
    const unsigned short* __restrict__ Qimg, // 16 x 2KB swizzled tile images
    float* __restrict__ G)                   // [NROWS][20] f32 packed
{
    __shared__ unsigned short Qs[16384];     // 32 KB

    const int tid  = threadIdx.x;
    const int w    = tid >> 6;
    const int lane = tid & 63;
    const int l15  = lane & 15;
    const int kg   = (lane >> 4) << 2;       // float index within 16
    const long row0 = (long)blockIdx.x * 128;

    // stage all of Q once (wave-uniform dests)
#pragma unroll
    for (int j = 0; j < 8; ++j) {
        const int off = (j * 4 + w) * 1024;
        gload_lds16((const char*)Qimg + off + lane * 16, (char*)Qs + off);
    }

    // per-lane A row pointers (fragment layout == coalesced global layout)
    long r0 = row0 + w * 32 + l15;      if (r0 >= NROWS) r0 = NROWS - 1;
    long r1 = r0 + 16;                  if (r1 >= NROWS) r1 = NROWS - 1;
    const float* a0 = A + r0 * INDIM + kg;
    const float* a1 = A + r1 * INDIM + kg;

    // B fragment byte addresses
    int brd0[2], brd1[2];
#pragma unroll
    for (int f = 0; f < 2; ++f) {
        brd0[f] = img_addr(f * 16 + l15, kg);
        brd1[f] = img_addr(f * 16 + l15, kg + 16);
    }

    f32x4_t acc[2][2];
#pragma unroll
    for (int i = 0; i < 2; ++i)
#pragma unroll
        for (int f = 0; f < 2; ++f)
#pragma unroll
            for (int r = 0; r < 4; ++r) acc[i][f][r] = 0.f;

    const char* bsb = (const char*)&Qs[0];

    float4 qA[4], qB[4], qC[4];   // depth-3 register queue (static names, rule #20)
    LOADC(qA, 0)
    LOADC(qB, 1)
    LOADC(qC, 2)
    __syncthreads();   // drain Q global_load_lds (once)

#pragma unroll
    for (int t = 0; t < 16; ++t) {
        Frag fa[2];
        if (t % 3 == 0)      CVT(fa, qA)
        else if (t % 3 == 1) CVT(fa, qB)
        else                 CVT(fa, qC)

        // refill the freed slot with chunk t+3 (waited 3 iterations later)
        if (t + 3 <= 15) {
            if (t % 3 == 0)      { LOADC(qA, t + 3) }
            else if (t % 3 == 1) { LOADC(qB, t + 3) }
            else                 { LOADC(qC, t + 3) }
        }

        Frag fb[2];
#pragma unroll
        for (int f = 0; f < 2; ++f) {
            fb[f].v4[0] = *(const bf16x4_t*)(bsb + t * 2048 + brd0[f]);
            fb[f].v4[1] = *(const bf16x4_t*)(bsb + t * 2048 + brd1[f]);
        }
#pragma unroll
        for (int ii = 0; ii < 2; ++ii)
#pragma unroll
            for (int f = 0; f < 2; ++f)
                acc[ii][f] = __builtin_amdgcn_mfma_f32_16x16x32_bf16(fa[ii].v8, fb[f].v8, acc[ii][f], 0, 0, 0);
    }

    // epilogue: packed G rows of 20 f32: [0,10) = f@Q1, [10,20) = f@Q2
    const int rq_ = (lane >> 4) << 2;
#pragma unroll
    for (int ii = 0; ii < 2; ++ii)
#pragma unroll
        for (int r = 0; r < 4; ++r) {
            long grow = row0 + w * 32 + ii * 16 + rq_ + r;
            if (l15 < NCLS && grow < NROWS) {
                G[grow * 20 + l15]      = acc[ii][0][r];
                G[grow * 20 + 10 + l15] = acc[ii][1][r];
            }
        }
}

// ---------------- epilogue: logits = leaky(g[n1][0:10] + g[n2][10:20]), log_softmax ----------------
__global__ __launch_bounds__(256) void k_epi(
    const float* __restrict__ G,
    const int* __restrict__ n1, const int* __restrict__ n2,
    float* __restrict__ Out) {
    const long i = (long)blockIdx.x * 256 + threadIdx.x;
    if (i >= NROWS) return;
    const float2* g1 = (const float2*)(G + (long)n1[i] * 20);
    const float2* g2 = (const float2*)(G + (long)n2[i] * 20 + 10);

    float x[NCLS];
#pragma unroll
    for (int j = 0; j < 5; ++j) {
        float2 a = g1[j], b = g2[j];
        x[2 * j]     = a.x + b.x;
        x[2 * j + 1] = a.y + b.y;
    }
    float m = -1e30f;
#pragma unroll
    for (int c = 0; c < NCLS; ++c) {
        x[c] = (x[c] >= 0.f) ? x[c] : LEAKY_ALPHA * x[c];
        m = fmaxf(m, x[c]);
    }
    float sum = 0.f;
#pragma unroll
    for (int c = 0; c < NCLS; ++c) sum += __expf(x[c] - m);
    const float lse = m + __logf(sum);
    float2* o = (float2*)(Out + i * NCLS);
#pragma unroll
    for (int j = 0; j < 5; ++j) {
        float2 v = {x[2 * j] - lse, x[2 * j + 1] - lse};
        o[j] = v;
    }
}

extern "C" void kernel_launch(void* const* d_in, const int* in_sizes, int n_in,
                              void* d_out, int out_size, void* d_ws, size_t ws_size,
                              hipStream_t stream) {
    const float* features = (const float*)d_in[0];
    const float* C  = (const float*)d_in[1];
    const float* W  = (const float*)d_in[2];
    const float* V  = (const float*)d_in[3];
    const int*   n1 = (const int*)d_in[4];
    const int*   n2 = (const int*)d_in[5];
    float* out = (float*)d_out;

    char* ws = (char*)d_ws;
    unsigned short* Qimg = (unsigned short*)ws;   // 32 KB
    float* G = (float*)(ws + 32768);              // 100000*20*4 = 8 MB

    hipLaunchKernelGGL(k_prep, dim3(8), dim3(256), 0, stream, C, W, V, Qimg);
    hipLaunchKernelGGL(k_gemm, dim3((NROWS + 127) / 128), dim3(256), 0, stream,
                       features, Qimg, G);
    hipLaunchKernelGGL(k_epi, dim3((NROWS + 255) / 256), dim3(256), 0, stream,
                       G, n1, n2, out);
}

// Round 8
// 69.378 us; speedup vs baseline: 1.0100x; 1.0100x over previous
//
#include <hip/hip_runtime.h>
#include <hip/hip_bf16.h>
#include <stdint.h>

#define NROWS 100000
#define INDIM 512
#define HID 128
#define NCLS 10
#define LEAKY_ALPHA 0.2f

typedef __bf16 bf16x8_t __attribute__((ext_vector_type(8)));
typedef __bf16 bf16x4_t __attribute__((ext_vector_type(4)));
typedef float f32x4_t __attribute__((ext_vector_type(4)));
typedef unsigned short ushort8_t __attribute__((ext_vector_type(8)));

union Frag {
    bf16x8_t v8;
    bf16x4_t v4[2];
    unsigned short u[8];
};

__device__ __forceinline__ unsigned short f2bf(float x) {
    union { __hip_bfloat16 b; unsigned short u; } cv;
    cv.b = __float2bfloat16(x);
    return cv.u;
}

// Byte address inside an [R x 32] bf16 tile image (rows paired into 128-B
// lines, 16-B units XOR-swizzled by pair&7). Bank-verified round 3.
__device__ __forceinline__ int img_addr(int r, int kk) {
    int p = r >> 1;
    int o = ((r & 1) << 6) | (kk << 1);
    return (p << 7) | ((((o >> 4) ^ (p & 7)) << 4) | (o & 15));
}

__device__ __forceinline__ void gload_lds16(const void* g, void* l) {
    __builtin_amdgcn_global_load_lds(
        (const __attribute__((address_space(1))) unsigned int*)g,
        (__attribute__((address_space(3))) unsigned int*)l, 16, 0, 0);
}

// ---------------- prep: Qimg = swizzled tile images of Q = [C@(W1@V) | C@(W2@V)] ----------------
__global__ __launch_bounds__(256) void k_prep(
    const float* __restrict__ C, const float* __restrict__ W, const float* __restrict__ V,
    unsigned short* __restrict__ Qimg) {
    __shared__ float Vl[HID * NCLS];
    __shared__ float Pl[2][HID][10];
    __shared__ float Cl[64][132];

    const int tid = threadIdx.x, b = blockIdx.x;
    for (int i = tid; i < HID * NCLS; i += 256) Vl[i] = V[i];
    __syncthreads();

    {
        const int half = tid >> 7, j = tid & 127;
        const float* wr = W + (half * HID + j) * HID;
        float s[NCLS];
#pragma unroll
        for (int c = 0; c < NCLS; ++c) s[c] = 0.f;
        for (int m = 0; m < HID; m += 4) {
            float4 wv = *reinterpret_cast<const float4*>(wr + m);
            float wa[4] = {wv.x, wv.y, wv.z, wv.w};
#pragma unroll
            for (int u = 0; u < 4; ++u)
#pragma unroll
                for (int c = 0; c < NCLS; ++c) s[c] += wa[u] * Vl[(m + u) * NCLS + c];
        }
#pragma unroll
        for (int c = 0; c < NCLS; ++c) Pl[half][j][c] = s[c];
    }
    const int k0 = b << 6;
    {
        const int kr = tid >> 2, seg = (tid & 3) << 5;
        const float4* src = reinterpret_cast<const float4*>(C + (k0 + kr) * HID + seg);
#pragma unroll
        for (int j = 0; j < 8; ++j)
            *reinterpret_cast<float4*>(&Cl[kr][seg + 4 * j]) = src[j];
    }
    __syncthreads();

    for (int e = tid; e < 64 * 32; e += 256) {
        const int n = e >> 6, kl = e & 63;
        const int half = n >> 4, c = n & 15;
        float s = 0.f;
        if (c < NCLS) {
#pragma unroll 4
            for (int j = 0; j < HID; ++j) s += Cl[kl][j] * Pl[half][j][c];
        }
        const int k = k0 + kl, t = k >> 5, kk = k & 31;
        *(unsigned short*)((char*)Qimg + t * 2048 + img_addr(n, kk)) = f2bf(s);
    }
}

// ---------------- thin GEMM: g = f @ Q, barrier-free + convert-ahead ----------------
// 4 waves x 32 rows. A: global -> depth-3 register queue -> (CVT one iter
// ahead) -> fa ping-pong regs -> MFMA. B frags ds_read one iter ahead.
// No LDS for A, no __syncthreads in the loop. Q in LDS (32 KB), staged once.
#define LOADC(dst, t)                                                        \
    dst[0] = *reinterpret_cast<const float4*>(a0 + (t) * 32);                \
    dst[1] = *reinterpret_cast<const float4*>(a0 + (t) * 32 + 16);           \
    dst[2] = *reinterpret_cast<const float4*>(a1 + (t) * 32);                \
    dst[3] = *reinterpret_cast<const float4*>(a1 + (t) * 32 + 16);

#define CVT(fa, s)                                                           \
    {                                                                        \
        _Pragma("unroll")                                                    \
        for (int e = 0; e < 4; ++e) {                                        \
            fa[0].u[e]     = f2bf(s[0][e]);                                  \
            fa[0].u[4 + e] = f2bf(s[1][e]);                                  \
            fa[1].u[e]     = f2bf(s[2][e]);                                  \
            fa[1].u[4 + e] = f2bf(s[3][e]);                                  \
        }                                                                    \
    }

#define READB(fb, t)                                                         \
    {                                                                        \
        _Pragma("unroll")                                                    \
        for (int f = 0; f < 2; ++f) {                                        \
            fb[f].v4[0] = *(const bf16x4_t*)(bsb + (t) * 2048 + brd0[f]);    \
            fb[f].v4[1] = *(const bf16x4_t*)(bsb + (t) * 2048 + brd1[f]);    \
        }                                                                    \
    }

#define MFMA4(fa, fb)                                                        \
    {                                                                        \
        _Pragma("unroll")                                                    \
        for (int ii = 0; ii < 2; ++ii)                                       \
            _Pragma("unroll")                                                \
            for (int f = 0; f < 2; ++f)                                      \
                acc[ii][f] = __builtin_amdgcn_mfma_f32_16x16x32_bf16(        \
                    fa[ii].v8, fb[f].v8, acc[ii][f], 0, 0, 0);               \
    }

__global__ __launch_bounds__(256, 3) void k_gemm(
    const float* __restrict__ A,             // [NROWS][512] f32
    const unsigned short* __restrict__ Qimg, // 16 x 2KB swizzled tile images
    float* __restrict__ G)                   // [NROWS][20] f32 packed
{
    __shared__ unsigned short Qs[16384];     // 32 KB

    const int tid  = threadIdx.x;
    const int w    = tid >> 6;
    const int lane = tid & 63;
    const int l15  = lane & 15;
    const int kg   = (lane >> 4) << 2;       // float index within 16
    const long row0 = (long)blockIdx.x * 128;

    // stage all of Q once (wave-uniform dests)
#pragma unroll
    for (int j = 0; j < 8; ++j) {
        const int off = (j * 4 + w) * 1024;
        gload_lds16((const char*)Qimg + off + lane * 16, (char*)Qs + off);
    }

    // per-lane A row pointers (fragment layout == coalesced global layout)
    long r0 = row0 + w * 32 + l15;      if (r0 >= NROWS) r0 = NROWS - 1;
    long r1 = r0 + 16;                  if (r1 >= NROWS) r1 = NROWS - 1;
    const float* a0 = A + r0 * INDIM + kg;
    const float* a1 = A + r1 * INDIM + kg;

    // B fragment byte addresses
    int brd0[2], brd1[2];
#pragma unroll
    for (int f = 0; f < 2; ++f) {
        brd0[f] = img_addr(f * 16 + l15, kg);
        brd1[f] = img_addr(f * 16 + l15, kg + 16);
    }

    f32x4_t acc[2][2];
#pragma unroll
    for (int i = 0; i < 2; ++i)
#pragma unroll
        for (int f = 0; f < 2; ++f)
#pragma unroll
            for (int r = 0; r < 4; ++r) acc[i][f][r] = 0.f;

    const char* bsb = (const char*)&Qs[0];

    // depth-3 load queue (chunk c lives in slot c%3); fa/fb ping-pong by parity
    float4 qA[4], qB[4], qC[4];
    Frag faE[2], faO[2], fbE[2], fbO[2];

    LOADC(qA, 0)
    LOADC(qB, 1)
    LOADC(qC, 2)
    __syncthreads();            // Q LDS ready (drains Q gload + qA/qB/qC)

    CVT(faE, qA)                // chunk 0 -> even frag set
    LOADC(qA, 3)                // slot A refilled with chunk 3
    READB(fbE, 0)

#pragma unroll
    for (int t = 0; t < 16; ++t) {
        // MFMA for chunk t: everything was prepared last iteration
        if ((t & 1) == 0) { MFMA4(faE, fbE) } else { MFMA4(faO, fbO) }

        if (t < 15) {
            // prepare chunk t+1 (overlaps the matrix pipe)
            if (((t + 1) & 1) == 0) { READB(fbE, t + 1) } else { READB(fbO, t + 1) }
            const int slot = (t + 1) % 3;   // q slot holding chunk t+1
            if ((t & 1) == 0) {
                if (slot == 0)      { CVT(faO, qA) }
                else if (slot == 1) { CVT(faO, qB) }
                else                { CVT(faO, qC) }
            } else {
                if (slot == 0)      { CVT(faE, qA) }
                else if (slot == 1) { CVT(faE, qB) }
                else                { CVT(faE, qC) }
            }
            // refill the just-consumed slot with chunk t+4 (3-iter cover)
            if (t + 4 <= 15) {
                if (slot == 0)      { LOADC(qA, t + 4) }
                else if (slot == 1) { LOADC(qB, t + 4) }
                else                { LOADC(qC, t + 4) }
            }
        }
    }

    // epilogue: packed G rows of 20 f32: [0,10) = f@Q1, [10,20) = f@Q2
    const int rq_ = (lane >> 4) << 2;
#pragma unroll
    for (int ii = 0; ii < 2; ++ii)
#pragma unroll
        for (int r = 0; r < 4; ++r) {
            long grow = row0 + w * 32 + ii * 16 + rq_ + r;
            if (l15 < NCLS && grow < NROWS) {
                G[grow * 20 + l15]      = acc[ii][0][r];
                G[grow * 20 + 10 + l15] = acc[ii][1][r];
            }
        }
}

// ---------------- epilogue: logits = leaky(g[n1][0:10] + g[n2][10:20]), log_softmax ----------------
__global__ __launch_bounds__(256) void k_epi(
    const float* __restrict__ G,
    const int* __restrict__ n1, const int* __restrict__ n2,
    float* __restrict__ Out) {
    const long i = (long)blockIdx.x * 256 + threadIdx.x;
    if (i >= NROWS) return;
    const float2* g1 = (const float2*)(G + (long)n1[i] * 20);
    const float2* g2 = (const float2*)(G + (long)n2[i] * 20 + 10);

    float x[NCLS];
#pragma unroll
    for (int j = 0; j < 5; ++j) {
        float2 a = g1[j], b = g2[j];
        x[2 * j]     = a.x + b.x;
        x[2 * j + 1] = a.y + b.y;
    }
    float m = -1e30f;
#pragma unroll
    for (int c = 0; c < NCLS; ++c) {
        x[c] = (x[c] >= 0.f) ? x[c] : LEAKY_ALPHA * x[c];
        m = fmaxf(m, x[c]);
    }
    float sum = 0.f;
#pragma unroll
    for (int c = 0; c < NCLS; ++c) sum += __expf(x[c] - m);
    const float lse = m + __logf(sum);
    float2* o = (float2*)(Out + i * NCLS);
#pragma unroll
    for (int j = 0; j < 5; ++j) {
        float2 v = {x[2 * j] - lse, x[2 * j + 1] - lse};
        o[j] = v;
    }
}

extern "C" void kernel_launch(void* const* d_in, const int* in_sizes, int n_in,
                              void* d_out, int out_size, void* d_ws, size_t ws_size,
                              hipStream_t stream) {
    const float* features = (const float*)d_in[0];
    const float* C  = (const float*)d_in[1];
    const float* W  = (const float*)d_in[2];
    const float* V  = (const float*)d_in[3];
    const int*   n1 = (const int*)d_in[4];
    const int*   n2 = (const int*)d_in[5];
    float* out = (float*)d_out;

    char* ws = (char*)d_ws;
    unsigned short* Qimg = (unsigned short*)ws;   // 32 KB
    float* G = (float*)(ws + 32768);              // 100000*20*4 = 8 MB

    hipLaunchKernelGGL(k_prep, dim3(8), dim3(256), 0, stream, C, W, V, Qimg);
    hipLaunchKernelGGL(k_gemm, dim3((NROWS + 127) / 128), dim3(256), 0, stream,
                       features, Qimg, G);
    hipLaunchKernelGGL(k_epi, dim3((NROWS + 255) / 256), dim3(256), 0, stream,
                       G, n1, n2, out);
}

// Round 9
// 64.067 us; speedup vs baseline: 1.0937x; 1.0829x over previous
//
#include <hip/hip_runtime.h>
#include <hip/hip_bf16.h>
#include <stdint.h>

#define NROWS 100000
#define INDIM 512
#define HID 128
#define NCLS 10
#define LEAKY_ALPHA 0.2f
#define GSTR 24   // G row stride (f32), 96 B = 16B-aligned

typedef __bf16 bf16x8_t __attribute__((ext_vector_type(8)));
typedef __bf16 bf16x4_t __attribute__((ext_vector_type(4)));
typedef float f32x4_t __attribute__((ext_vector_type(4)));
typedef unsigned short ushort8_t __attribute__((ext_vector_type(8)));

union Frag {
    bf16x8_t v8;
    bf16x4_t v4[2];
    unsigned short u[8];
};

__device__ __forceinline__ unsigned short f2bf(float x) {
    union { __hip_bfloat16 b; unsigned short u; } cv;
    cv.b = __float2bfloat16(x);
    return cv.u;
}

// Byte address inside an [R x 32] bf16 tile image (rows paired into 128-B
// lines, 16-B units XOR-swizzled by pair&7). Bank-verified round 3.
__device__ __forceinline__ int img_addr(int r, int kk) {
    int p = r >> 1;
    int o = ((r & 1) << 6) | (kk << 1);
    return (p << 7) | ((((o >> 4) ^ (p & 7)) << 4) | (o & 15));
}

__device__ __forceinline__ void gload_lds16(const void* g, void* l) {
    __builtin_amdgcn_global_load_lds(
        (const __attribute__((address_space(1))) unsigned int*)g,
        (__attribute__((address_space(3))) unsigned int*)l, 16, 0, 0);
}

// ---------------- prep: Qimg = swizzled tile images of Q = [C@(W1@V) | C@(W2@V)] ----------------
// 16 blocks; block b produces k-rows [b*32, b*32+32) of both halves.
__global__ __launch_bounds__(256) void k_prep(
    const float* __restrict__ C, const float* __restrict__ W, const float* __restrict__ V,
    unsigned short* __restrict__ Qimg) {
    __shared__ float Vl[HID * NCLS];
    __shared__ float Pl[2][HID][10];
    __shared__ float Cl[32][132];

    const int tid = threadIdx.x, b = blockIdx.x;
    for (int i = tid; i < HID * NCLS; i += 256) Vl[i] = V[i];
    __syncthreads();

    // P[half][j][c] = dot(W[half*128 + j, :], V[:, c]); one (half,j) per thread
    {
        const int half = tid >> 7, j = tid & 127;
        const float* wr = W + (half * HID + j) * HID;
        float s[NCLS];
#pragma unroll
        for (int c = 0; c < NCLS; ++c) s[c] = 0.f;
        for (int m = 0; m < HID; m += 4) {
            float4 wv = *reinterpret_cast<const float4*>(wr + m);
            float wa[4] = {wv.x, wv.y, wv.z, wv.w};
#pragma unroll
            for (int u = 0; u < 4; ++u)
#pragma unroll
                for (int c = 0; c < NCLS; ++c) s[c] += wa[u] * Vl[(m + u) * NCLS + c];
        }
#pragma unroll
        for (int c = 0; c < NCLS; ++c) Pl[half][j][c] = s[c];
    }
    // stage C rows [k0, k0+32)
    const int k0 = b << 5;
    {
        const int kr = tid >> 3, ns = (tid & 7) << 4;
        const float4* src = reinterpret_cast<const float4*>(C + (k0 + kr) * HID + ns);
#pragma unroll
        for (int j = 0; j < 4; ++j)
            *reinterpret_cast<float4*>(&Cl[kr][ns + 4 * j]) = src[j];
    }
    __syncthreads();

    // Q entries: 32 k x 32 n (tile index t == b, kk == kl)
    for (int e = tid; e < 32 * 32; e += 256) {
        const int n = e >> 5, kl = e & 31;
        const int half = n >> 4, c = n & 15;
        float s = 0.f;
        if (c < NCLS) {
#pragma unroll 4
            for (int j = 0; j < HID; ++j) s += Cl[kl][j] * Pl[half][j][c];
        }
        *(unsigned short*)((char*)Qimg + b * 2048 + img_addr(n, kl)) = f2bf(s);
    }
}

// ---------------- thin GEMM: g = f @ Q  (barrier-free wave-private staging) ----------------
// BM=128, BK=32, 4 waves. A staging is WAVE-PRIVATE: wave w's threads stage
// rows [32w,32w+32) which only wave w's fragments read -> no __syncthreads in
// the main loop (same-wave DS ordering via lgkmcnt). Depth-3 register queue
// (chunk c in slot c%3, refill t+4). Q staged once via global_load_lds.
__global__ __launch_bounds__(256, 3) void k_gemm(
    const float* __restrict__ A,             // [NROWS][512] f32
    const unsigned short* __restrict__ Qimg, // 16 x 2KB swizzled tile images
    float* __restrict__ G)                   // [NROWS][GSTR] f32
{
    __shared__ unsigned short Qs[16384];     // 32 KB
    __shared__ unsigned short As[2][4096];   // 2 x 8 KB

    const int tid  = threadIdx.x;
    const int w    = tid >> 6;
    const int lane = tid & 63;
    const int l15  = lane & 15;
    const int kg   = (lane >> 4) << 2;
    const long row0 = (long)blockIdx.x * 128;

    // stage all of Q once (wave-uniform dests)
#pragma unroll
    for (int j = 0; j < 8; ++j) {
        const int off = (j * 4 + w) * 1024;
        gload_lds16((const char*)Qimg + off + lane * 16, (char*)Qs + off);
    }

    // A staging: thread -> (row tid>>1, 16-float half); wave-private rows
    const int ar_s = tid >> 1;
    const int kh   = (tid & 1) << 4;
    long gr = row0 + ar_s;
    if (gr >= NROWS) gr = NROWS - 1;
    const float* asrc = A + gr * INDIM + kh;
    const int aw0 = img_addr(ar_s, kh);
    const int aw1 = img_addr(ar_s, kh + 8);

    int ard0[2], ard1[2], brd0[2], brd1[2];
#pragma unroll
    for (int ii = 0; ii < 2; ++ii) {
        int r = w * 32 + ii * 16 + l15;
        ard0[ii] = img_addr(r, kg);
        ard1[ii] = img_addr(r, kg + 16);
    }
#pragma unroll
    for (int f = 0; f < 2; ++f) {
        brd0[f] = img_addr(f * 16 + l15, kg);
        brd1[f] = img_addr(f * 16 + l15, kg + 16);
    }

    f32x4_t acc[2][2];
#pragma unroll
    for (int i = 0; i < 2; ++i)
#pragma unroll
        for (int f = 0; f < 2; ++f)
#pragma unroll
            for (int r = 0; r < 4; ++r) acc[i][f][r] = 0.f;

    const char* asb = (const char*)&As[0][0];
    const char* bsb = (const char*)&Qs[0];

    float4 qA[4], qB[4], qC[4];   // slot c%3 holds chunk c (static names)

    // prologue: chunk 0 staged directly; chunks 1,2,3 -> slots 1,2,0
    {
        float4 v[4];
#pragma unroll
        for (int j = 0; j < 4; ++j) v[j] = *reinterpret_cast<const float4*>(asrc + 4 * j);
        ushort8_t lo, hi;
#pragma unroll
        for (int e = 0; e < 4; ++e) {
            lo[e] = f2bf(v[0][e]); lo[4 + e] = f2bf(v[1][e]);
            hi[e] = f2bf(v[2][e]); hi[4 + e] = f2bf(v[3][e]);
        }
        *(ushort8_t*)((char*)asb + aw0) = lo;
        *(ushort8_t*)((char*)asb + aw1) = hi;
    }
#pragma unroll
    for (int j = 0; j < 4; ++j) qB[j] = *reinterpret_cast<const float4*>(asrc + 32 + 4 * j);
#pragma unroll
    for (int j = 0; j < 4; ++j) qC[j] = *reinterpret_cast<const float4*>(asrc + 64 + 4 * j);
#pragma unroll
    for (int j = 0; j < 4; ++j) qA[j] = *reinterpret_cast<const float4*>(asrc + 96 + 4 * j);
    __syncthreads();   // the ONLY barrier: Q visible to all waves

#pragma unroll
    for (int t = 0; t < 16; ++t) {
        const int cur = t & 1;

        Frag fa[2], fb[2];
#pragma unroll
        for (int ii = 0; ii < 2; ++ii) {
            fa[ii].v4[0] = *(const bf16x4_t*)(asb + cur * 8192 + ard0[ii]);
            fa[ii].v4[1] = *(const bf16x4_t*)(asb + cur * 8192 + ard1[ii]);
        }
#pragma unroll
        for (int f = 0; f < 2; ++f) {
            fb[f].v4[0] = *(const bf16x4_t*)(bsb + t * 2048 + brd0[f]);
            fb[f].v4[1] = *(const bf16x4_t*)(bsb + t * 2048 + brd1[f]);
        }
#pragma unroll
        for (int ii = 0; ii < 2; ++ii)
#pragma unroll
            for (int f = 0; f < 2; ++f)
                acc[ii][f] = __builtin_amdgcn_mfma_f32_16x16x32_bf16(fa[ii].v8, fb[f].v8, acc[ii][f], 0, 0, 0);

        if (t < 15) {
            // convert chunk t+1 (slot (t+1)%3), write into the other buffer
            const int slot = (t + 1) % 3;
            ushort8_t lo, hi;
            if (slot == 0) {
#pragma unroll
                for (int e = 0; e < 4; ++e) {
                    lo[e] = f2bf(qA[0][e]); lo[4 + e] = f2bf(qA[1][e]);
                    hi[e] = f2bf(qA[2][e]); hi[4 + e] = f2bf(qA[3][e]);
                }
            } else if (slot == 1) {
#pragma unroll
                for (int e = 0; e < 4; ++e) {
                    lo[e] = f2bf(qB[0][e]); lo[4 + e] = f2bf(qB[1][e]);
                    hi[e] = f2bf(qB[2][e]); hi[4 + e] = f2bf(qB[3][e]);
                }
            } else {
#pragma unroll
                for (int e = 0; e < 4; ++e) {
                    lo[e] = f2bf(qC[0][e]); lo[4 + e] = f2bf(qC[1][e]);
                    hi[e] = f2bf(qC[2][e]); hi[4 + e] = f2bf(qC[3][e]);
                }
            }
            *(ushort8_t*)((char*)asb + (cur ^ 1) * 8192 + aw0) = lo;
            *(ushort8_t*)((char*)asb + (cur ^ 1) * 8192 + aw1) = hi;

            // refill the just-freed slot with chunk t+4 (3-iter latency cover)
            if (t + 4 <= 15) {
                const float* src = asrc + (t + 4) * 32;
                if (slot == 0) {
#pragma unroll
                    for (int j = 0; j < 4; ++j) qA[j] = *reinterpret_cast<const float4*>(src + 4 * j);
                } else if (slot == 1) {
#pragma unroll
                    for (int j = 0; j < 4; ++j) qB[j] = *reinterpret_cast<const float4*>(src + 4 * j);
                } else {
#pragma unroll
                    for (int j = 0; j < 4; ++j) qC[j] = *reinterpret_cast<const float4*>(src + 4 * j);
                }
            }
        }
    }

    // epilogue: G[row][l15] = f@Q1, G[row][12+l15] = f@Q2 (16B-aligned slots)
    const int rq_ = (lane >> 4) << 2;
#pragma unroll
    for (int ii = 0; ii < 2; ++ii)
#pragma unroll
        for (int r = 0; r < 4; ++r) {
            long grow = row0 + w * 32 + ii * 16 + rq_ + r;
            if (l15 < NCLS && grow < NROWS) {
                G[grow * GSTR + l15]      = acc[ii][0][r];
                G[grow * GSTR + 12 + l15] = acc[ii][1][r];
            }
        }
}

// ---------------- epilogue: logits = leaky(g[n1][0:10] + g[n2][12:22]), log_softmax ----------------
__global__ __launch_bounds__(256) void k_epi(
    const float* __restrict__ G,
    const int* __restrict__ n1, const int* __restrict__ n2,
    float* __restrict__ Out) {
    const long i = (long)blockIdx.x * 256 + threadIdx.x;
    if (i >= NROWS) return;
    const float* g1 = G + (long)n1[i] * GSTR;
    const float* g2 = G + (long)n2[i] * GSTR + 12;

    float4 a0 = *(const float4*)(g1);
    float4 a1 = *(const float4*)(g1 + 4);
    float2 a2 = *(const float2*)(g1 + 8);
    float4 b0 = *(const float4*)(g2);
    float4 b1 = *(const float4*)(g2 + 4);
    float2 b2 = *(const float2*)(g2 + 8);

    float x[NCLS] = {a0.x + b0.x, a0.y + b0.y, a0.z + b0.z, a0.w + b0.w,
                     a1.x + b1.x, a1.y + b1.y, a1.z + b1.z, a1.w + b1.w,
                     a2.x + b2.x, a2.y + b2.y};
    float m = -1e30f;
#pragma unroll
    for (int c = 0; c < NCLS; ++c) {
        x[c] = (x[c] >= 0.f) ? x[c] : LEAKY_ALPHA * x[c];
        m = fmaxf(m, x[c]);
    }
    float sum = 0.f;
#pragma unroll
    for (int c = 0; c < NCLS; ++c) sum += __expf(x[c] - m);
    const float lse = m + __logf(sum);
    float2* o = (float2*)(Out + i * NCLS);
#pragma unroll
    for (int j = 0; j < 5; ++j) {
        float2 v = {x[2 * j] - lse, x[2 * j + 1] - lse};
        o[j] = v;
    }
}

extern "C" void kernel_launch(void* const* d_in, const int* in_sizes, int n_in,
                              void* d_out, int out_size, void* d_ws, size_t ws_size,
                              hipStream_t stream) {
    const float* features = (const float*)d_in[0];
    const float* C  = (const float*)d_in[1];
    const float* W  = (const float*)d_in[2];
    const float* V  = (const float*)d_in[3];
    const int*   n1 = (const int*)d_in[4];
    const int*   n2 = (const int*)d_in[5];
    float* out = (float*)d_out;

    char* ws = (char*)d_ws;
    unsigned short* Qimg = (unsigned short*)ws;   // 32 KB
    float* G = (float*)(ws + 32768);              // 100000*24*4 = 9.6 MB

    hipLaunchKernelGGL(k_prep, dim3(16), dim3(256), 0, stream, C, W, V, Qimg);
    hipLaunchKernelGGL(k_gemm, dim3((NROWS + 127) / 128), dim3(256), 0, stream,
                       features, Qimg, G);
    hipLaunchKernelGGL(k_epi, dim3((NROWS + 255) / 256), dim3(256), 0, stream,
                       G, n1, n2, out);
}